// Round 16
// baseline (440.432 us; speedup 1.0000x reference)
//
#include <hip/hip_runtime.h>
#include <hip/hip_bf16.h>
#include <stdint.h>

#define NEXP 16
#define KSEL 4
#define HDIM 2048
#define IDIM 1024
#define TTOK 2048
#define MAXTILES 80
#define NTA 16                   // gemmA n-tiles (IDIM/64)
#define NTB 32                   // gemmB n-tiles (HDIM/64)
#define MAXBA (MAXTILES * NTA)   // 1280
#define MAXBB (MAXTILES * NTB)   // 2560

typedef __attribute__((ext_vector_type(8))) short bf16x8;
typedef __attribute__((ext_vector_type(4))) float f32x4;
typedef __attribute__((ext_vector_type(4))) unsigned int u32x4;
typedef unsigned int u32;

__device__ __forceinline__ uint32_t pack2(float a, float b) {
  __hip_bfloat162 h = __float22bfloat162_rn(float2{a, b});
  uint32_t u;
  __builtin_memcpy(&u, &h, 4);
  return u;
}
__device__ __forceinline__ ushort bf1(float a) {
  __hip_bfloat16 h = __float2bfloat16(a);
  ushort u;
  __builtin_memcpy(&u, &h, 2);
  return u;
}
__device__ __forceinline__ float bf2f(ushort u) {
  uint32_t v = (uint32_t)u << 16;
  float f;
  __builtin_memcpy(&f, &v, 4);
  return f;
}
// async global->LDS, 16B per lane; linear dest, per-lane (gathered/swizzled)
// source address (m97/m173 pattern).
__device__ __forceinline__ void gload16(const void* g, void* l) {
  __builtin_amdgcn_global_load_lds(
      (const __attribute__((address_space(1))) u32*)g,
      (__attribute__((address_space(3))) u32*)l, 16, 0, 0);
}
// bf16 tile [rows][32 bf16]: stored linear, source chunk pre-XOR'd,
// read chunk XOR'd -> conflict-free (0 conflicts verified R3-R15).
__device__ __forceinline__ int swzread(int row, int q) {
  return row * 32 + ((q ^ ((row >> 1) & 3)) << 3);
}

// ---------------- cvt: fp32 -> bf16 streaming (NT source loads) ----------
__global__ __launch_bounds__(256) void cvtw_kernel(
    const float* __restrict__ src, ushort* __restrict__ dst, int n8)
{
  const int stride = gridDim.x * 256;
  for (int i = blockIdx.x * 256 + threadIdx.x; i < n8; i += stride) {
    f32x4 a = __builtin_nontemporal_load(((const f32x4*)src) + i * 2);
    f32x4 b = __builtin_nontemporal_load(((const f32x4*)src) + i * 2 + 1);
    uint4 t;
    t.x = pack2(a[0], a[1]); t.y = pack2(a[2], a[3]);
    t.z = pack2(b[0], b[1]); t.w = pack2(b[2], b[3]);
    ((uint4*)dst)[i] = t;   // normal store: keep bf16 weights L3-resident
  }
}

// ------- router: logits, top-4, softmax, x->bf16. NO atomics. -------
__global__ __launch_bounds__(256) void router_kernel(
    const float* __restrict__ x, const float* __restrict__ gw,
    ushort* __restrict__ xb, int* __restrict__ topk_id,
    float* __restrict__ topk_w)
{
  const int wid = threadIdx.x >> 6;
  const int lane = threadIdx.x & 63;
  const int t = blockIdx.x * 4 + wid;
  const float4* x4 = (const float4*)(x + (size_t)t * HDIM);
  const float4* gw4 = (const float4*)gw;
  float acc[NEXP];
#pragma unroll
  for (int e = 0; e < NEXP; ++e) acc[e] = 0.f;
#pragma unroll
  for (int i = 0; i < HDIM / 256; ++i) {
    const int idx = i * 64 + lane;
    float4 xv = x4[idx];
    uint2 xp;
    xp.x = pack2(xv.x, xv.y);
    xp.y = pack2(xv.z, xv.w);
    *(uint2*)(xb + (size_t)t * HDIM + idx * 4) = xp;
#pragma unroll
    for (int e = 0; e < NEXP; ++e) {
      float4 wv = gw4[e * (HDIM / 4) + idx];
      acc[e] += xv.x * wv.x + xv.y * wv.y + xv.z * wv.z + xv.w * wv.w;
    }
  }
#pragma unroll
  for (int e = 0; e < NEXP; ++e) {
#pragma unroll
    for (int off = 32; off >= 1; off >>= 1)
      acc[e] += __shfl_xor(acc[e], off);
  }
  if (lane == 0) {
    unsigned taken = 0;
    float vals[KSEL];
    int ids[KSEL];
#pragma unroll
    for (int k = 0; k < KSEL; ++k) {
      float bv = -3.4e38f; int bi = 0;
      for (int e = 0; e < NEXP; ++e)
        if (!((taken >> e) & 1u) && acc[e] > bv) { bv = acc[e]; bi = e; }
      taken |= 1u << bi; vals[k] = bv; ids[k] = bi;
    }
    float m = vals[0], s = 0.f, w[KSEL];
#pragma unroll
    for (int k = 0; k < KSEL; ++k) { w[k] = __expf(vals[k] - m); s += w[k]; }
    float is = 1.f / s;
#pragma unroll
    for (int k = 0; k < KSEL; ++k) {
      topk_id[t * KSEL + k] = ids[k];
      topk_w[t * KSEL + k] = w[k] * is;
    }
  }
}

// --- plan+scatter, single block: LDS histogram/cursors, no global atomics --
__global__ __launch_bounds__(1024) void plan_scatter_kernel(
    const int* __restrict__ topk_id, int* __restrict__ counts,
    int* __restrict__ offsets, int* __restrict__ nWA, int* __restrict__ nWB,
    int* __restrict__ wlA, int* __restrict__ wlB,
    int* __restrict__ rowTok, int* __restrict__ inv)
{
  __shared__ int cnt[NEXP], off[NEXP], cur[NEXP], tiles[NEXP], pre[NEXP];
  const int tid = threadIdx.x;
  if (tid < NEXP) { cnt[tid] = 0; cur[tid] = 0; }
  __syncthreads();
  for (int i = tid; i < TTOK * KSEL; i += 1024)
    atomicAdd(&cnt[topk_id[i]], 1);               // LDS atomics (fast)
  __syncthreads();
  if (tid == 0) {
    int s = 0, p = 0;
    for (int e = 0; e < NEXP; ++e) {
      off[e] = s; s += cnt[e];
      tiles[e] = (cnt[e] + 127) >> 7;
      pre[e] = p; p += tiles[e];
    }
    *nWA = p * NTA;
    *nWB = p * NTB;
  }
  __syncthreads();
  if (tid < NEXP) {
    counts[tid] = cnt[tid];
    offsets[tid] = off[tid];
    const int e = tid, T = tiles[e];
    int idx = pre[e] * NTA;
    for (int nt = 0; nt < NTA; ++nt)
      for (int mt = 0; mt < T; ++mt)
        wlA[idx++] = (e << 12) | (nt << 6) | mt;
  } else if (tid < 2 * NEXP) {
    const int e = tid - NEXP, T = tiles[e];
    int idx = pre[e] * NTB;
    for (int nt = 0; nt < NTB; ++nt)
      for (int mt = 0; mt < T; ++mt)
        wlB[idx++] = (e << 12) | (nt << 6) | mt;
  }
  for (int i = tid; i < TTOK * KSEL; i += 1024) {
    const int e = topk_id[i];
    const int pos = atomicAdd(&cur[e], 1);        // LDS atomic
    const int row = off[e] + pos;
    rowTok[row] = i >> 2;
    inv[i] = row;
  }
}

// --- gemmA: out[rows][1024] = gathered_x . W^T. BM=128 BN=64 BK=32 --------
// m97 staging (global_load_lds + swizzle), 4 waves in 2x2, 4x2 frags each.
// BN halved vs R15 -> 1024 active blocks (4/CU) for latency hiding.
__global__ __launch_bounds__(256) void gemmA_kernel(
    const ushort* __restrict__ xb, const ushort* __restrict__ wb,
    const int* __restrict__ rowTok, const int* __restrict__ counts,
    const int* __restrict__ offsets, const int* __restrict__ nW,
    const int* __restrict__ wl, ushort* __restrict__ outb)
{
  const int nTot = *nW;
  const int L = (blockIdx.x & 7) * (MAXBA / 8) + (blockIdx.x >> 3);
  if (L >= nTot) return;
  const int w = wl[L];
  const int e = w >> 12, nt = (w >> 6) & 63, mt = w & 63;
  const int n_e = counts[e], rowbase = offsets[e];

  __shared__ ushort As[2][128 * 32];
  __shared__ ushort Bs[2][64 * 32];

  const int tid = threadIdx.x;
  const int r0 = tid >> 2;
  const int ck = tid & 3;
  const int sch = (ck ^ ((r0 >> 1) & 3)) << 3;

  const int ar0 = mt * 128 + r0, ar1 = ar0 + 64;
  const int tok0 = rowTok[rowbase + (ar0 < n_e ? ar0 : n_e - 1)];
  const int tok1 = rowTok[rowbase + (ar1 < n_e ? ar1 : n_e - 1)];
  const ushort* pA0 = xb + (size_t)tok0 * HDIM + sch;
  const ushort* pA1 = xb + (size_t)tok1 * HDIM + sch;
  const size_t wbase = (size_t)e * IDIM * HDIM;
  const ushort* pB0 = wb + wbase + (size_t)(nt * 64 + r0) * HDIM + sch;

  const int lane = tid & 63;
  const int wid = tid >> 6;
  const int wr = (wid >> 1) << 6;   // wave rows 0/64
  const int wc = (wid & 1) << 5;    // wave cols 0/32
  const int lr = lane & 15;
  const int q = lane >> 4;

  f32x4 acc[4][2];
#pragma unroll
  for (int i = 0; i < 4; ++i)
#pragma unroll
    for (int j = 0; j < 2; ++j) acc[i][j] = (f32x4){0.f, 0.f, 0.f, 0.f};

  auto STAGE = [&](int b) {
    gload16(pA0, &As[b][tid * 8]);
    gload16(pA1, &As[b][2048 + tid * 8]);
    gload16(pB0, &Bs[b][tid * 8]);
    pA0 += 32; pA1 += 32; pB0 += 32;
  };

  const int NTK = HDIM / 32;  // 64
  STAGE(0);
  __syncthreads();
  int buf = 0;
  for (int kt = 0; kt < NTK; ++kt) {
    if (kt + 1 < NTK) STAGE(buf ^ 1);
    bf16x8 af[4], bfr[2];
#pragma unroll
    for (int mi = 0; mi < 4; ++mi)
      af[mi] = *(const bf16x8*)&As[buf][swzread(wr + mi * 16 + lr, q)];
#pragma unroll
    for (int ni = 0; ni < 2; ++ni)
      bfr[ni] = *(const bf16x8*)&Bs[buf][swzread(wc + ni * 16 + lr, q)];
#pragma unroll
    for (int mi = 0; mi < 4; ++mi)
#pragma unroll
      for (int ni = 0; ni < 2; ++ni)
        acc[mi][ni] = __builtin_amdgcn_mfma_f32_16x16x32_bf16(af[mi], bfr[ni], acc[mi][ni], 0, 0, 0);
    __syncthreads();
    buf ^= 1;
  }

#pragma unroll
  for (int mi = 0; mi < 4; ++mi) {
#pragma unroll
    for (int ni = 0; ni < 2; ++ni) {
      const int col = nt * 64 + wc + ni * 16 + lr;
#pragma unroll
      for (int r = 0; r < 4; ++r) {
        const int mrow = mt * 128 + wr + mi * 16 + q * 4 + r;
        if (mrow < n_e)
          outb[(size_t)(rowbase + mrow) * IDIM + col] = bf1(acc[mi][ni][r]);
      }
    }
  }
}

// --- gemmB: po[rows][2048] = hbuf . w2^T. BM=128 BN=64 BK=32 --------------
__global__ __launch_bounds__(256) void gemmB_kernel(
    const ushort* __restrict__ hb, const ushort* __restrict__ wb,
    const int* __restrict__ counts, const int* __restrict__ offsets,
    const int* __restrict__ nW, const int* __restrict__ wl,
    ushort* __restrict__ po)
{
  const int nTot = *nW;
  const int L = (blockIdx.x & 7) * (MAXBB / 8) + (blockIdx.x >> 3);
  if (L >= nTot) return;
  const int w = wl[L];
  const int e = w >> 12, nt = (w >> 6) & 63, mt = w & 63;
  const int n_e = counts[e], rowbase = offsets[e];

  __shared__ ushort As[2][128 * 32];
  __shared__ ushort Bs[2][64 * 32];

  const int tid = threadIdx.x;
  const int r0 = tid >> 2;
  const int ck = tid & 3;
  const int sch = (ck ^ ((r0 >> 1) & 3)) << 3;

  const int ar0 = mt * 128 + r0, ar1 = ar0 + 64;
  const int g0 = rowbase + (ar0 < n_e ? ar0 : n_e - 1);
  const int g1 = rowbase + (ar1 < n_e ? ar1 : n_e - 1);
  const ushort* pA0 = hb + (size_t)g0 * IDIM + sch;
  const ushort* pA1 = hb + (size_t)g1 * IDIM + sch;
  const size_t wbase = (size_t)e * HDIM * IDIM;
  const ushort* pB0 = wb + wbase + (size_t)(nt * 64 + r0) * IDIM + sch;

  const int lane = tid & 63;
  const int wid = tid >> 6;
  const int wr = (wid >> 1) << 6;
  const int wc = (wid & 1) << 5;
  const int lr = lane & 15;
  const int q = lane >> 4;

  f32x4 acc[4][2];
#pragma unroll
  for (int i = 0; i < 4; ++i)
#pragma unroll
    for (int j = 0; j < 2; ++j) acc[i][j] = (f32x4){0.f, 0.f, 0.f, 0.f};

  auto STAGE = [&](int b) {
    gload16(pA0, &As[b][tid * 8]);
    gload16(pA1, &As[b][2048 + tid * 8]);
    gload16(pB0, &Bs[b][tid * 8]);
    pA0 += 32; pA1 += 32; pB0 += 32;
  };

  const int NTK = IDIM / 32;  // 32
  STAGE(0);
  __syncthreads();
  int buf = 0;
  for (int kt = 0; kt < NTK; ++kt) {
    if (kt + 1 < NTK) STAGE(buf ^ 1);
    bf16x8 af[4], bfr[2];
#pragma unroll
    for (int mi = 0; mi < 4; ++mi)
      af[mi] = *(const bf16x8*)&As[buf][swzread(wr + mi * 16 + lr, q)];
#pragma unroll
    for (int ni = 0; ni < 2; ++ni)
      bfr[ni] = *(const bf16x8*)&Bs[buf][swzread(wc + ni * 16 + lr, q)];
#pragma unroll
    for (int mi = 0; mi < 4; ++mi)
#pragma unroll
      for (int ni = 0; ni < 2; ++ni)
        acc[mi][ni] = __builtin_amdgcn_mfma_f32_16x16x32_bf16(af[mi], bfr[ni], acc[mi][ni], 0, 0, 0);
    __syncthreads();
    buf ^= 1;
  }

#pragma unroll
  for (int mi = 0; mi < 4; ++mi) {
#pragma unroll
    for (int ni = 0; ni < 2; ++ni) {
      const int col = nt * 64 + wc + ni * 16 + lr;
#pragma unroll
      for (int r = 0; r < 4; ++r) {
        const int mrow = mt * 128 + wr + mi * 16 + q * 4 + r;
        if (mrow < n_e)
          po[(size_t)(rowbase + mrow) * HDIM + col] = bf1(acc[mi][ni][r]);
      }
    }
  }
}

// ---------------- silu: h = silu(g) * u, elementwise bf16 ----------------
__global__ __launch_bounds__(256) void silu_kernel(
    const ushort* __restrict__ g, const ushort* __restrict__ u,
    ushort* __restrict__ h, int n8)
{
  const int stride = gridDim.x * 256;
  for (int i = blockIdx.x * 256 + threadIdx.x; i < n8; i += stride) {
    u32x4 gv = __builtin_nontemporal_load(((const u32x4*)g) + i);
    u32x4 uv = __builtin_nontemporal_load(((const u32x4*)u) + i);
    uint4 hv;
#pragma unroll
    for (int wd = 0; wd < 4; ++wd) {
      const uint32_t gw2 = gv[wd], uw2 = uv[wd];
      const float g0 = bf2f((ushort)(gw2 & 0xffff));
      const float g1 = bf2f((ushort)(gw2 >> 16));
      const float u0 = bf2f((ushort)(uw2 & 0xffff));
      const float u1 = bf2f((ushort)(uw2 >> 16));
      const float h0 = (g0 / (1.f + __expf(-g0))) * u0;
      const float h1 = (g1 / (1.f + __expf(-g1))) * u1;
      (&hv.x)[wd] = pack2(h0, h1);
    }
    ((uint4*)h)[i] = hv;
  }
}

// ---------------- combine: out[t] = sum_k w_k * po[row_k] -----------------
__global__ __launch_bounds__(256) void combine_kernel(
    const ushort* __restrict__ po, const int* __restrict__ inv,
    const float* __restrict__ tw, float* __restrict__ out)
{
  const int t = blockIdx.x;
  const int r0 = inv[t * 4 + 0], r1 = inv[t * 4 + 1];
  const int r2 = inv[t * 4 + 2], r3 = inv[t * 4 + 3];
  const float w0 = tw[t * 4 + 0], w1 = tw[t * 4 + 1];
  const float w2v = tw[t * 4 + 2], w3 = tw[t * 4 + 3];
  const int i = threadIdx.x;
  uint4 v0 = *(const uint4*)(po + (size_t)r0 * HDIM + i * 8);
  uint4 v1 = *(const uint4*)(po + (size_t)r1 * HDIM + i * 8);
  uint4 v2 = *(const uint4*)(po + (size_t)r2 * HDIM + i * 8);
  uint4 v3 = *(const uint4*)(po + (size_t)r3 * HDIM + i * 8);
  float o[8];
#pragma unroll
  for (int w = 0; w < 4; ++w) {
    const uint32_t a = (&v0.x)[w], b = (&v1.x)[w], c = (&v2.x)[w], d = (&v3.x)[w];
    o[w * 2 + 0] = w0 * __builtin_bit_cast(float, a << 16) +
                   w1 * __builtin_bit_cast(float, b << 16) +
                   w2v * __builtin_bit_cast(float, c << 16) +
                   w3 * __builtin_bit_cast(float, d << 16);
    o[w * 2 + 1] = w0 * __builtin_bit_cast(float, a & 0xffff0000u) +
                   w1 * __builtin_bit_cast(float, b & 0xffff0000u) +
                   w2v * __builtin_bit_cast(float, c & 0xffff0000u) +
                   w3 * __builtin_bit_cast(float, d & 0xffff0000u);
  }
  float4* o4 = (float4*)(out + (size_t)t * HDIM + i * 8);
  o4[0] = (float4){o[0], o[1], o[2], o[3]};
  o4[1] = (float4){o[4], o[5], o[6], o[7]};
}

extern "C" void kernel_launch(void* const* d_in, const int* in_sizes, int n_in,
                              void* d_out, int out_size, void* d_ws, size_t ws_size,
                              hipStream_t stream) {
  const float* x   = (const float*)d_in[0];
  const float* gw  = (const float*)d_in[1];
  const float* w1g = (const float*)d_in[2];
  const float* w1u = (const float*)d_in[3];
  const float* w2  = (const float*)d_in[4];
  float* out = (float*)d_out;

  char* ws = (char*)d_ws;
  // R9/R15 layout:
  // xb 8MB @0; wbuf 64MB @8M (w1g -> w1u -> w2 serially); gbuf 16MB @75M;
  // ubuf 16MB @92M; hbuf 16MB @109M; po 32MB @125M; idx @159M; ctrl.
  ushort* xb   = (ushort*)(ws + 0);
  ushort* wbuf = (ushort*)(ws + 8388608);
  ushort* gbuf = (ushort*)(ws + 75497472);
  ushort* ubuf = (ushort*)(ws + 92274688);
  ushort* hbuf = (ushort*)(ws + 109051904);
  ushort* po   = (ushort*)(ws + 125829120);
  int*    tkid   = (int*)(ws + 159383552);
  float*  tkw    = (float*)(ws + 159383552 + 32768);
  int*    rowTok = (int*)(ws + 159383552 + 65536);
  int*    inv    = (int*)(ws + 159383552 + 98304);
  int*    ctrl   = (int*)(ws + 159514624);
  int* counts  = ctrl;           // 16
  int* offsets = ctrl + 32;      // 17
  int* nWA     = ctrl + 50;      // 1
  int* nWB     = ctrl + 51;      // 1
  int* wlA     = ctrl + 64;      // MAXBA (1280)
  int* wlB     = ctrl + 64 + MAXBA;  // MAXBB (2560)

  const int NW8 = (NEXP * IDIM * HDIM) / 8;  // per weight tensor

  router_kernel<<<TTOK / 4, 256, 0, stream>>>(x, gw, xb, tkid, tkw);
  plan_scatter_kernel<<<1, 1024, 0, stream>>>(tkid, counts, offsets, nWA, nWB,
                                              wlA, wlB, rowTok, inv);
  // gate pass
  cvtw_kernel<<<2048, 256, 0, stream>>>(w1g, wbuf, NW8);
  gemmA_kernel<<<MAXBA, 256, 0, stream>>>(xb, wbuf, rowTok, counts, offsets,
                                          nWA, wlA, gbuf);
  // up pass (wbuf reused; stream order serializes)
  cvtw_kernel<<<2048, 256, 0, stream>>>(w1u, wbuf, NW8);
  gemmA_kernel<<<MAXBA, 256, 0, stream>>>(xb, wbuf, rowTok, counts, offsets,
                                          nWA, wlA, ubuf);
  // h = silu(g) * u
  silu_kernel<<<2048, 256, 0, stream>>>(gbuf, ubuf, hbuf, (TTOK * KSEL * IDIM) / 8);
  // down pass
  cvtw_kernel<<<2048, 256, 0, stream>>>(w2, wbuf, NW8);
  gemmB_kernel<<<MAXBB, 256, 0, stream>>>(hbuf, wbuf, counts, offsets,
                                          nWB, wlB, po);
  combine_kernel<<<TTOK, 256, 0, stream>>>(po, inv, tkw, out);
}

// Round 17
// 393.100 us; speedup vs baseline: 1.1204x; 1.1204x over previous
//
#include <hip/hip_runtime.h>
#include <hip/hip_bf16.h>
#include <stdint.h>

#define NEXP 16
#define KSEL 4
#define HDIM 2048
#define IDIM 1024
#define TTOK 2048
#define MAXTILES 80
#define NTA 8                    // gemmA n-tiles (IDIM/128)
#define NTB 16                   // gemmB n-tiles (HDIM/128)
#define MAXBA (MAXTILES * NTA)   // 640
#define MAXBB (MAXTILES * NTB)   // 1280

typedef __attribute__((ext_vector_type(8))) short bf16x8;
typedef __attribute__((ext_vector_type(4))) float f32x4;
typedef __attribute__((ext_vector_type(4))) unsigned int u32x4;
typedef unsigned int u32;

__device__ __forceinline__ uint32_t pack2(float a, float b) {
  __hip_bfloat162 h = __float22bfloat162_rn(float2{a, b});
  uint32_t u;
  __builtin_memcpy(&u, &h, 4);
  return u;
}
__device__ __forceinline__ ushort bf1(float a) {
  __hip_bfloat16 h = __float2bfloat16(a);
  ushort u;
  __builtin_memcpy(&u, &h, 2);
  return u;
}
__device__ __forceinline__ float bf2f(ushort u) {
  uint32_t v = (uint32_t)u << 16;
  float f;
  __builtin_memcpy(&f, &v, 4);
  return f;
}
// async global->LDS, 16B per lane; linear dest, per-lane (gathered/swizzled)
// source address (m97/m173 pattern).
__device__ __forceinline__ void gload16(const void* g, void* l) {
  __builtin_amdgcn_global_load_lds(
      (const __attribute__((address_space(1))) u32*)g,
      (__attribute__((address_space(3))) u32*)l, 16, 0, 0);
}
// bf16 tile [rows][32 bf16]: stored linear, source chunk pre-XOR'd,
// read chunk XOR'd -> conflict-free (0 conflicts verified R3-R16).
__device__ __forceinline__ int swzread(int row, int q) {
  return row * 32 + ((q ^ ((row >> 1) & 3)) << 3);
}

// ---------------- cvt: fp32 -> bf16 streaming (NT source loads) ----------
__global__ __launch_bounds__(256) void cvtw_kernel(
    const float* __restrict__ src, ushort* __restrict__ dst, int n8)
{
  const int stride = gridDim.x * 256;
  for (int i = blockIdx.x * 256 + threadIdx.x; i < n8; i += stride) {
    f32x4 a = __builtin_nontemporal_load(((const f32x4*)src) + i * 2);
    f32x4 b = __builtin_nontemporal_load(((const f32x4*)src) + i * 2 + 1);
    uint4 t;
    t.x = pack2(a[0], a[1]); t.y = pack2(a[2], a[3]);
    t.z = pack2(b[0], b[1]); t.w = pack2(b[2], b[3]);
    ((uint4*)dst)[i] = t;   // normal store: keep bf16 weights L3-resident
  }
}

// ------- router: logits, top-4, softmax, x->bf16. NO atomics. -------
__global__ __launch_bounds__(256) void router_kernel(
    const float* __restrict__ x, const float* __restrict__ gw,
    ushort* __restrict__ xb, int* __restrict__ topk_id,
    float* __restrict__ topk_w)
{
  const int wid = threadIdx.x >> 6;
  const int lane = threadIdx.x & 63;
  const int t = blockIdx.x * 4 + wid;
  const float4* x4 = (const float4*)(x + (size_t)t * HDIM);
  const float4* gw4 = (const float4*)gw;
  float acc[NEXP];
#pragma unroll
  for (int e = 0; e < NEXP; ++e) acc[e] = 0.f;
#pragma unroll
  for (int i = 0; i < HDIM / 256; ++i) {
    const int idx = i * 64 + lane;
    float4 xv = x4[idx];
    uint2 xp;
    xp.x = pack2(xv.x, xv.y);
    xp.y = pack2(xv.z, xv.w);
    *(uint2*)(xb + (size_t)t * HDIM + idx * 4) = xp;
#pragma unroll
    for (int e = 0; e < NEXP; ++e) {
      float4 wv = gw4[e * (HDIM / 4) + idx];
      acc[e] += xv.x * wv.x + xv.y * wv.y + xv.z * wv.z + xv.w * wv.w;
    }
  }
#pragma unroll
  for (int e = 0; e < NEXP; ++e) {
#pragma unroll
    for (int off = 32; off >= 1; off >>= 1)
      acc[e] += __shfl_xor(acc[e], off);
  }
  if (lane == 0) {
    unsigned taken = 0;
    float vals[KSEL];
    int ids[KSEL];
#pragma unroll
    for (int k = 0; k < KSEL; ++k) {
      float bv = -3.4e38f; int bi = 0;
      for (int e = 0; e < NEXP; ++e)
        if (!((taken >> e) & 1u) && acc[e] > bv) { bv = acc[e]; bi = e; }
      taken |= 1u << bi; vals[k] = bv; ids[k] = bi;
    }
    float m = vals[0], s = 0.f, w[KSEL];
#pragma unroll
    for (int k = 0; k < KSEL; ++k) { w[k] = __expf(vals[k] - m); s += w[k]; }
    float is = 1.f / s;
#pragma unroll
    for (int k = 0; k < KSEL; ++k) {
      topk_id[t * KSEL + k] = ids[k];
      topk_w[t * KSEL + k] = w[k] * is;
    }
  }
}

// --- plan+scatter, single block: LDS histogram/cursors, no global atomics --
__global__ __launch_bounds__(1024) void plan_scatter_kernel(
    const int* __restrict__ topk_id, int* __restrict__ counts,
    int* __restrict__ offsets, int* __restrict__ nWA, int* __restrict__ nWB,
    int* __restrict__ wlA, int* __restrict__ wlB,
    int* __restrict__ rowTok, int* __restrict__ inv)
{
  __shared__ int cnt[NEXP], off[NEXP], cur[NEXP], tiles[NEXP], pre[NEXP];
  const int tid = threadIdx.x;
  if (tid < NEXP) { cnt[tid] = 0; cur[tid] = 0; }
  __syncthreads();
  for (int i = tid; i < TTOK * KSEL; i += 1024)
    atomicAdd(&cnt[topk_id[i]], 1);               // LDS atomics (fast)
  __syncthreads();
  if (tid == 0) {
    int s = 0, p = 0;
    for (int e = 0; e < NEXP; ++e) {
      off[e] = s; s += cnt[e];
      tiles[e] = (cnt[e] + 127) >> 7;
      pre[e] = p; p += tiles[e];
    }
    *nWA = p * NTA;
    *nWB = p * NTB;
  }
  __syncthreads();
  if (tid < NEXP) {
    counts[tid] = cnt[tid];
    offsets[tid] = off[tid];
    const int e = tid, T = tiles[e];
    int idx = pre[e] * NTA;
    for (int nt = 0; nt < NTA; ++nt)
      for (int mt = 0; mt < T; ++mt)
        wlA[idx++] = (e << 12) | (nt << 6) | mt;
  } else if (tid < 2 * NEXP) {
    const int e = tid - NEXP, T = tiles[e];
    int idx = pre[e] * NTB;
    for (int nt = 0; nt < NTB; ++nt)
      for (int mt = 0; mt < T; ++mt)
        wlB[idx++] = (e << 12) | (nt << 6) | mt;
  }
  for (int i = tid; i < TTOK * KSEL; i += 1024) {
    const int e = topk_id[i];
    const int pos = atomicAdd(&cur[e], 1);        // LDS atomic
    const int row = off[e] + pos;
    rowTok[row] = i >> 2;
    inv[i] = row;
  }
}

// ------- gemmA: out[rows][1024] = gathered_x . W^T. BM=128 BN=128 BK=32 ---
// T3/T4: 3-buffer LDS pipeline, counted vmcnt(4) + raw barrier — prefetch
// loads stay in flight across barriers (never drained to 0 in steady state).
__global__ __launch_bounds__(256) void gemmA_kernel(
    const ushort* __restrict__ xb, const ushort* __restrict__ wb,
    const int* __restrict__ rowTok, const int* __restrict__ counts,
    const int* __restrict__ offsets, const int* __restrict__ nW,
    const int* __restrict__ wl, ushort* __restrict__ outb)
{
  const int nTot = *nW;
  const int L = (blockIdx.x & 7) * (MAXBA / 8) + (blockIdx.x >> 3);
  if (L >= nTot) return;
  const int w = wl[L];
  const int e = w >> 12, nt = (w >> 6) & 63, mt = w & 63;
  const int n_e = counts[e], rowbase = offsets[e];

  __shared__ ushort As[3][128 * 32];
  __shared__ ushort Bs[3][128 * 32];

  const int tid = threadIdx.x;
  const int r0 = tid >> 2;
  const int ck = tid & 3;
  const int sch = (ck ^ ((r0 >> 1) & 3)) << 3;

  const int ar0 = mt * 128 + r0, ar1 = ar0 + 64;
  const int tok0 = rowTok[rowbase + (ar0 < n_e ? ar0 : n_e - 1)];
  const int tok1 = rowTok[rowbase + (ar1 < n_e ? ar1 : n_e - 1)];
  const ushort* pA0 = xb + (size_t)tok0 * HDIM + sch;
  const ushort* pA1 = xb + (size_t)tok1 * HDIM + sch;
  const size_t wbase = (size_t)e * IDIM * HDIM;
  const ushort* pB0 = wb + wbase + (size_t)(nt * 128 + r0) * HDIM + sch;
  const ushort* pB1 = wb + wbase + (size_t)(nt * 128 + r0 + 64) * HDIM + sch;

  const int lane = tid & 63;
  const int wid = tid >> 6;
  const int wr = (wid >> 1) << 6;
  const int wc = (wid & 1) << 6;
  const int lr = lane & 15;
  const int q = lane >> 4;

  f32x4 acc[4][4];
#pragma unroll
  for (int i = 0; i < 4; ++i)
#pragma unroll
    for (int j = 0; j < 4; ++j) acc[i][j] = (f32x4){0.f, 0.f, 0.f, 0.f};

  auto STAGE = [&](int b) {
    gload16(pA0, &As[b][tid * 8]);
    gload16(pA1, &As[b][2048 + tid * 8]);
    gload16(pB0, &Bs[b][tid * 8]);
    gload16(pB1, &Bs[b][2048 + tid * 8]);
    pA0 += 32; pA1 += 32; pB0 += 32; pB1 += 32;
  };

  const int NTK = HDIM / 32;  // 64
  STAGE(0);
  STAGE(1);
  asm volatile("s_waitcnt vmcnt(4)" ::: "memory");  // stage0 landed
  __builtin_amdgcn_s_barrier();
  __builtin_amdgcn_sched_barrier(0);
  int buf = 0;
  for (int kt = 0; kt < NTK; ++kt) {
    // stage kt+2 into the buffer whose readers finished before last barrier
    if (kt + 2 < NTK) STAGE(buf == 0 ? 2 : buf - 1);
    bf16x8 af[4], bfr[4];
#pragma unroll
    for (int mi = 0; mi < 4; ++mi)
      af[mi] = *(const bf16x8*)&As[buf][swzread(wr + mi * 16 + lr, q)];
#pragma unroll
    for (int ni = 0; ni < 4; ++ni)
      bfr[ni] = *(const bf16x8*)&Bs[buf][swzread(wc + ni * 16 + lr, q)];
#pragma unroll
    for (int mi = 0; mi < 4; ++mi)
#pragma unroll
      for (int ni = 0; ni < 4; ++ni)
        acc[mi][ni] = __builtin_amdgcn_mfma_f32_16x16x32_bf16(af[mi], bfr[ni], acc[mi][ni], 0, 0, 0);
    if (kt + 1 < NTK) {
      if (kt + 2 < NTK)
        asm volatile("s_waitcnt vmcnt(4)" ::: "memory");  // kt+1 landed, kt+2 in flight
      else
        asm volatile("s_waitcnt vmcnt(0)" ::: "memory");  // tail: drain last stage
      __builtin_amdgcn_s_barrier();
      __builtin_amdgcn_sched_barrier(0);
    }
    buf = (buf == 2) ? 0 : buf + 1;
  }

#pragma unroll
  for (int mi = 0; mi < 4; ++mi) {
#pragma unroll
    for (int ni = 0; ni < 4; ++ni) {
      const int col = nt * 128 + wc + ni * 16 + lr;
#pragma unroll
      for (int r = 0; r < 4; ++r) {
        const int mrow = mt * 128 + wr + mi * 16 + q * 4 + r;
        if (mrow < n_e)
          outb[(size_t)(rowbase + mrow) * IDIM + col] = bf1(acc[mi][ni][r]);
      }
    }
  }
}

// ------- gemmB: po[rows][2048] = hbuf . w2^T. Same 3-buffer pipeline. -----
__global__ __launch_bounds__(256) void gemmB_kernel(
    const ushort* __restrict__ hb, const ushort* __restrict__ wb,
    const int* __restrict__ counts, const int* __restrict__ offsets,
    const int* __restrict__ nW, const int* __restrict__ wl,
    ushort* __restrict__ po)
{
  const int nTot = *nW;
  const int L = (blockIdx.x & 7) * (MAXBB / 8) + (blockIdx.x >> 3);
  if (L >= nTot) return;
  const int w = wl[L];
  const int e = w >> 12, nt = (w >> 6) & 63, mt = w & 63;
  const int n_e = counts[e], rowbase = offsets[e];

  __shared__ ushort As[3][128 * 32];
  __shared__ ushort Bs[3][128 * 32];

  const int tid = threadIdx.x;
  const int r0 = tid >> 2;
  const int ck = tid & 3;
  const int sch = (ck ^ ((r0 >> 1) & 3)) << 3;

  const int ar0 = mt * 128 + r0, ar1 = ar0 + 64;
  const int g0 = rowbase + (ar0 < n_e ? ar0 : n_e - 1);
  const int g1 = rowbase + (ar1 < n_e ? ar1 : n_e - 1);
  const ushort* pA0 = hb + (size_t)g0 * IDIM + sch;
  const ushort* pA1 = hb + (size_t)g1 * IDIM + sch;
  const size_t wbase = (size_t)e * HDIM * IDIM;
  const ushort* pB0 = wb + wbase + (size_t)(nt * 128 + r0) * IDIM + sch;
  const ushort* pB1 = wb + wbase + (size_t)(nt * 128 + r0 + 64) * IDIM + sch;

  const int lane = tid & 63;
  const int wid = tid >> 6;
  const int wr = (wid >> 1) << 6;
  const int wc = (wid & 1) << 6;
  const int lr = lane & 15;
  const int q = lane >> 4;

  f32x4 acc[4][4];
#pragma unroll
  for (int i = 0; i < 4; ++i)
#pragma unroll
    for (int j = 0; j < 4; ++j) acc[i][j] = (f32x4){0.f, 0.f, 0.f, 0.f};

  auto STAGE = [&](int b) {
    gload16(pA0, &As[b][tid * 8]);
    gload16(pA1, &As[b][2048 + tid * 8]);
    gload16(pB0, &Bs[b][tid * 8]);
    gload16(pB1, &Bs[b][2048 + tid * 8]);
    pA0 += 32; pA1 += 32; pB0 += 32; pB1 += 32;
  };

  const int NTK = IDIM / 32;  // 32
  STAGE(0);
  STAGE(1);
  asm volatile("s_waitcnt vmcnt(4)" ::: "memory");
  __builtin_amdgcn_s_barrier();
  __builtin_amdgcn_sched_barrier(0);
  int buf = 0;
  for (int kt = 0; kt < NTK; ++kt) {
    if (kt + 2 < NTK) STAGE(buf == 0 ? 2 : buf - 1);
    bf16x8 af[4], bfr[4];
#pragma unroll
    for (int mi = 0; mi < 4; ++mi)
      af[mi] = *(const bf16x8*)&As[buf][swzread(wr + mi * 16 + lr, q)];
#pragma unroll
    for (int ni = 0; ni < 4; ++ni)
      bfr[ni] = *(const bf16x8*)&Bs[buf][swzread(wc + ni * 16 + lr, q)];
#pragma unroll
    for (int mi = 0; mi < 4; ++mi)
#pragma unroll
      for (int ni = 0; ni < 4; ++ni)
        acc[mi][ni] = __builtin_amdgcn_mfma_f32_16x16x32_bf16(af[mi], bfr[ni], acc[mi][ni], 0, 0, 0);
    if (kt + 1 < NTK) {
      if (kt + 2 < NTK)
        asm volatile("s_waitcnt vmcnt(4)" ::: "memory");
      else
        asm volatile("s_waitcnt vmcnt(0)" ::: "memory");
      __builtin_amdgcn_s_barrier();
      __builtin_amdgcn_sched_barrier(0);
    }
    buf = (buf == 2) ? 0 : buf + 1;
  }

#pragma unroll
  for (int mi = 0; mi < 4; ++mi) {
#pragma unroll
    for (int ni = 0; ni < 4; ++ni) {
      const int col = nt * 128 + wc + ni * 16 + lr;
#pragma unroll
      for (int r = 0; r < 4; ++r) {
        const int mrow = mt * 128 + wr + mi * 16 + q * 4 + r;
        if (mrow < n_e)
          po[(size_t)(rowbase + mrow) * HDIM + col] = bf1(acc[mi][ni][r]);
      }
    }
  }
}

// ---------------- silu: h = silu(g) * u, elementwise bf16 ----------------
__global__ __launch_bounds__(256) void silu_kernel(
    const ushort* __restrict__ g, const ushort* __restrict__ u,
    ushort* __restrict__ h, int n8)
{
  const int stride = gridDim.x * 256;
  for (int i = blockIdx.x * 256 + threadIdx.x; i < n8; i += stride) {
    u32x4 gv = __builtin_nontemporal_load(((const u32x4*)g) + i);
    u32x4 uv = __builtin_nontemporal_load(((const u32x4*)u) + i);
    uint4 hv;
#pragma unroll
    for (int wd = 0; wd < 4; ++wd) {
      const uint32_t gw2 = gv[wd], uw2 = uv[wd];
      const float g0 = bf2f((ushort)(gw2 & 0xffff));
      const float g1 = bf2f((ushort)(gw2 >> 16));
      const float u0 = bf2f((ushort)(uw2 & 0xffff));
      const float u1 = bf2f((ushort)(uw2 >> 16));
      const float h0 = (g0 / (1.f + __expf(-g0))) * u0;
      const float h1 = (g1 / (1.f + __expf(-g1))) * u1;
      (&hv.x)[wd] = pack2(h0, h1);
    }
    ((uint4*)h)[i] = hv;
  }
}

// ---------------- combine: out[t] = sum_k w_k * po[row_k] -----------------
__global__ __launch_bounds__(256) void combine_kernel(
    const ushort* __restrict__ po, const int* __restrict__ inv,
    const float* __restrict__ tw, float* __restrict__ out)
{
  const int t = blockIdx.x;
  const int r0 = inv[t * 4 + 0], r1 = inv[t * 4 + 1];
  const int r2 = inv[t * 4 + 2], r3 = inv[t * 4 + 3];
  const float w0 = tw[t * 4 + 0], w1 = tw[t * 4 + 1];
  const float w2v = tw[t * 4 + 2], w3 = tw[t * 4 + 3];
  const int i = threadIdx.x;
  uint4 v0 = *(const uint4*)(po + (size_t)r0 * HDIM + i * 8);
  uint4 v1 = *(const uint4*)(po + (size_t)r1 * HDIM + i * 8);
  uint4 v2 = *(const uint4*)(po + (size_t)r2 * HDIM + i * 8);
  uint4 v3 = *(const uint4*)(po + (size_t)r3 * HDIM + i * 8);
  float o[8];
#pragma unroll
  for (int w = 0; w < 4; ++w) {
    const uint32_t a = (&v0.x)[w], b = (&v1.x)[w], c = (&v2.x)[w], d = (&v3.x)[w];
    o[w * 2 + 0] = w0 * __builtin_bit_cast(float, a << 16) +
                   w1 * __builtin_bit_cast(float, b << 16) +
                   w2v * __builtin_bit_cast(float, c << 16) +
                   w3 * __builtin_bit_cast(float, d << 16);
    o[w * 2 + 1] = w0 * __builtin_bit_cast(float, a & 0xffff0000u) +
                   w1 * __builtin_bit_cast(float, b & 0xffff0000u) +
                   w2v * __builtin_bit_cast(float, c & 0xffff0000u) +
                   w3 * __builtin_bit_cast(float, d & 0xffff0000u);
  }
  float4* o4 = (float4*)(out + (size_t)t * HDIM + i * 8);
  o4[0] = (float4){o[0], o[1], o[2], o[3]};
  o4[1] = (float4){o[4], o[5], o[6], o[7]};
}

extern "C" void kernel_launch(void* const* d_in, const int* in_sizes, int n_in,
                              void* d_out, int out_size, void* d_ws, size_t ws_size,
                              hipStream_t stream) {
  const float* x   = (const float*)d_in[0];
  const float* gw  = (const float*)d_in[1];
  const float* w1g = (const float*)d_in[2];
  const float* w1u = (const float*)d_in[3];
  const float* w2  = (const float*)d_in[4];
  float* out = (float*)d_out;

  char* ws = (char*)d_ws;
  // R9/R15 layout:
  // xb 8MB @0; wbuf 64MB @8M (w1g -> w1u -> w2 serially); gbuf 16MB @75M;
  // ubuf 16MB @92M; hbuf 16MB @109M; po 32MB @125M; idx @159M; ctrl.
  ushort* xb   = (ushort*)(ws + 0);
  ushort* wbuf = (ushort*)(ws + 8388608);
  ushort* gbuf = (ushort*)(ws + 75497472);
  ushort* ubuf = (ushort*)(ws + 92274688);
  ushort* hbuf = (ushort*)(ws + 109051904);
  ushort* po   = (ushort*)(ws + 125829120);
  int*    tkid   = (int*)(ws + 159383552);
  float*  tkw    = (float*)(ws + 159383552 + 32768);
  int*    rowTok = (int*)(ws + 159383552 + 65536);
  int*    inv    = (int*)(ws + 159383552 + 98304);
  int*    ctrl   = (int*)(ws + 159514624);
  int* counts  = ctrl;           // 16
  int* offsets = ctrl + 32;      // 17
  int* nWA     = ctrl + 50;      // 1
  int* nWB     = ctrl + 51;      // 1
  int* wlA     = ctrl + 64;      // MAXBA (640)
  int* wlB     = ctrl + 64 + MAXBA;  // MAXBB (1280)

  const int NW8 = (NEXP * IDIM * HDIM) / 8;  // per weight tensor

  router_kernel<<<TTOK / 4, 256, 0, stream>>>(x, gw, xb, tkid, tkw);
  plan_scatter_kernel<<<1, 1024, 0, stream>>>(tkid, counts, offsets, nWA, nWB,
                                              wlA, wlB, rowTok, inv);
  // gate pass
  cvtw_kernel<<<2048, 256, 0, stream>>>(w1g, wbuf, NW8);
  gemmA_kernel<<<MAXBA, 256, 0, stream>>>(xb, wbuf, rowTok, counts, offsets,
                                          nWA, wlA, gbuf);
  // up pass (wbuf reused; stream order serializes)
  cvtw_kernel<<<2048, 256, 0, stream>>>(w1u, wbuf, NW8);
  gemmA_kernel<<<MAXBA, 256, 0, stream>>>(xb, wbuf, rowTok, counts, offsets,
                                          nWA, wlA, ubuf);
  // h = silu(g) * u
  silu_kernel<<<2048, 256, 0, stream>>>(gbuf, ubuf, hbuf, (TTOK * KSEL * IDIM) / 8);
  // down pass
  cvtw_kernel<<<2048, 256, 0, stream>>>(w2, wbuf, NW8);
  gemmB_kernel<<<MAXBB, 256, 0, stream>>>(hbuf, wbuf, counts, offsets,
                                          nWB, wlB, po);
  combine_kernel<<<TTOK, 256, 0, stream>>>(po, inv, tkw, out);
}

// Round 18
// 350.046 us; speedup vs baseline: 1.2582x; 1.1230x over previous
//
#include <hip/hip_runtime.h>
#include <hip/hip_bf16.h>
#include <stdint.h>

#define NEXP 16
#define KSEL 4
#define HDIM 2048
#define IDIM 1024
#define TTOK 2048
#define MAXTILES 80
#define NTA 8                    // gemmA n-tiles (IDIM/128)
#define NTB 16                   // gemmB n-tiles (HDIM/128)
#define MAXBA (MAXTILES * NTA)   // 640
#define MAXBB (MAXTILES * NTB)   // 1280
#define NCVT 1024                // piggyback cvt blocks
#define NW8 ((NEXP * IDIM * HDIM) / 8)

typedef __attribute__((ext_vector_type(8))) short bf16x8;
typedef __attribute__((ext_vector_type(4))) float f32x4;
typedef __attribute__((ext_vector_type(4))) unsigned int u32x4;
typedef unsigned int u32;

__device__ __forceinline__ uint32_t pack2(float a, float b) {
  __hip_bfloat162 h = __float22bfloat162_rn(float2{a, b});
  uint32_t u;
  __builtin_memcpy(&u, &h, 4);
  return u;
}
__device__ __forceinline__ ushort bf1(float a) {
  __hip_bfloat16 h = __float2bfloat16(a);
  ushort u;
  __builtin_memcpy(&u, &h, 2);
  return u;
}
__device__ __forceinline__ float bf2f(ushort u) {
  uint32_t v = (uint32_t)u << 16;
  float f;
  __builtin_memcpy(&f, &v, 4);
  return f;
}
// async global->LDS, 16B per lane; linear dest, per-lane (gathered/swizzled)
// source address (m97/m173 pattern).
__device__ __forceinline__ void gload16(const void* g, void* l) {
  __builtin_amdgcn_global_load_lds(
      (const __attribute__((address_space(1))) u32*)g,
      (__attribute__((address_space(3))) u32*)l, 16, 0, 0);
}
// bf16 tile [rows][32 bf16]: stored linear, source chunk pre-XOR'd,
// read chunk XOR'd -> conflict-free (0 conflicts verified R3-R17).
__device__ __forceinline__ int swzread(int row, int q) {
  return row * 32 + ((q ^ ((row >> 1) & 3)) << 3);
}
// fp32 -> bf16 streaming body (NT loads), grid-strided over nblk blocks.
__device__ __forceinline__ void cvt_body(const float* __restrict__ src,
                                         ushort* __restrict__ dst,
                                         int blk, int nblk) {
  const int stride = nblk * 256;
  for (int i = blk * 256 + (int)threadIdx.x; i < NW8; i += stride) {
    f32x4 a = __builtin_nontemporal_load(((const f32x4*)src) + i * 2);
    f32x4 b = __builtin_nontemporal_load(((const f32x4*)src) + i * 2 + 1);
    uint4 t;
    t.x = pack2(a[0], a[1]); t.y = pack2(a[2], a[3]);
    t.z = pack2(b[0], b[1]); t.w = pack2(b[2], b[3]);
    ((uint4*)dst)[i] = t;
  }
}

// ------- router (blocks 0..511) + piggyback cvt w1g (blocks 512+) -------
__global__ __launch_bounds__(256) void router_kernel(
    const float* __restrict__ x, const float* __restrict__ gw,
    ushort* __restrict__ xb, int* __restrict__ topk_id,
    float* __restrict__ topk_w, const float* __restrict__ cvsrc,
    ushort* __restrict__ cvdst)
{
  if (blockIdx.x >= TTOK / 4) {
    cvt_body(cvsrc, cvdst, blockIdx.x - TTOK / 4, NCVT);
    return;
  }
  const int wid = threadIdx.x >> 6;
  const int lane = threadIdx.x & 63;
  const int t = blockIdx.x * 4 + wid;
  const float4* x4 = (const float4*)(x + (size_t)t * HDIM);
  const float4* gw4 = (const float4*)gw;
  float acc[NEXP];
#pragma unroll
  for (int e = 0; e < NEXP; ++e) acc[e] = 0.f;
#pragma unroll
  for (int i = 0; i < HDIM / 256; ++i) {
    const int idx = i * 64 + lane;
    float4 xv = x4[idx];
    uint2 xp;
    xp.x = pack2(xv.x, xv.y);
    xp.y = pack2(xv.z, xv.w);
    *(uint2*)(xb + (size_t)t * HDIM + idx * 4) = xp;
#pragma unroll
    for (int e = 0; e < NEXP; ++e) {
      float4 wv = gw4[e * (HDIM / 4) + idx];
      acc[e] += xv.x * wv.x + xv.y * wv.y + xv.z * wv.z + xv.w * wv.w;
    }
  }
#pragma unroll
  for (int e = 0; e < NEXP; ++e) {
#pragma unroll
    for (int off = 32; off >= 1; off >>= 1)
      acc[e] += __shfl_xor(acc[e], off);
  }
  if (lane == 0) {
    unsigned taken = 0;
    float vals[KSEL];
    int ids[KSEL];
#pragma unroll
    for (int k = 0; k < KSEL; ++k) {
      float bv = -3.4e38f; int bi = 0;
      for (int e = 0; e < NEXP; ++e)
        if (!((taken >> e) & 1u) && acc[e] > bv) { bv = acc[e]; bi = e; }
      taken |= 1u << bi; vals[k] = bv; ids[k] = bi;
    }
    float m = vals[0], s = 0.f, w[KSEL];
#pragma unroll
    for (int k = 0; k < KSEL; ++k) { w[k] = __expf(vals[k] - m); s += w[k]; }
    float is = 1.f / s;
#pragma unroll
    for (int k = 0; k < KSEL; ++k) {
      topk_id[t * KSEL + k] = ids[k];
      topk_w[t * KSEL + k] = w[k] * is;
    }
  }
}

// --- plan+scatter, single block: LDS histogram/cursors, no global atomics --
__global__ __launch_bounds__(1024) void plan_scatter_kernel(
    const int* __restrict__ topk_id, int* __restrict__ counts,
    int* __restrict__ offsets, int* __restrict__ nWA, int* __restrict__ nWB,
    int* __restrict__ wlA, int* __restrict__ wlB,
    int* __restrict__ rowTok, int* __restrict__ inv)
{
  __shared__ int cnt[NEXP], off[NEXP], cur[NEXP], tiles[NEXP], pre[NEXP];
  const int tid = threadIdx.x;
  if (tid < NEXP) { cnt[tid] = 0; cur[tid] = 0; }
  __syncthreads();
  for (int i = tid; i < TTOK * KSEL; i += 1024)
    atomicAdd(&cnt[topk_id[i]], 1);               // LDS atomics (fast)
  __syncthreads();
  if (tid == 0) {
    int s = 0, p = 0;
    for (int e = 0; e < NEXP; ++e) {
      off[e] = s; s += cnt[e];
      tiles[e] = (cnt[e] + 127) >> 7;
      pre[e] = p; p += tiles[e];
    }
    *nWA = p * NTA;
    *nWB = p * NTB;
  }
  __syncthreads();
  if (tid < NEXP) {
    counts[tid] = cnt[tid];
    offsets[tid] = off[tid];
    const int e = tid, T = tiles[e];
    int idx = pre[e] * NTA;
    for (int nt = 0; nt < NTA; ++nt)
      for (int mt = 0; mt < T; ++mt)
        wlA[idx++] = (e << 12) | (nt << 6) | mt;
  } else if (tid < 2 * NEXP) {
    const int e = tid - NEXP, T = tiles[e];
    int idx = pre[e] * NTB;
    for (int nt = 0; nt < NTB; ++nt)
      for (int mt = 0; mt < T; ++mt)
        wlB[idx++] = (e << 12) | (nt << 6) | mt;
  }
  for (int i = tid; i < TTOK * KSEL; i += 1024) {
    const int e = topk_id[i];
    const int pos = atomicAdd(&cur[e], 1);        // LDS atomic
    const int row = off[e] + pos;
    rowTok[row] = i >> 2;
    inv[i] = row;
  }
}

// ------- gemmA (blocks 0..MAXBA-1) + piggyback cvt of NEXT weights -------
// GEMM body is the pristine R15 kernel (2-buffer, __syncthreads).
__global__ __launch_bounds__(256) void gemmA_kernel(
    const ushort* __restrict__ xb, const ushort* __restrict__ wb,
    const int* __restrict__ rowTok, const int* __restrict__ counts,
    const int* __restrict__ offsets, const int* __restrict__ nW,
    const int* __restrict__ wl, ushort* __restrict__ outb,
    const float* __restrict__ cvsrc, ushort* __restrict__ cvdst)
{
  if (blockIdx.x >= MAXBA) {
    cvt_body(cvsrc, cvdst, blockIdx.x - MAXBA, NCVT);
    return;
  }
  const int nTot = *nW;
  const int L = (blockIdx.x & 7) * (MAXBA / 8) + (blockIdx.x >> 3);
  if (L >= nTot) return;
  const int w = wl[L];
  const int e = w >> 12, nt = (w >> 6) & 63, mt = w & 63;
  const int n_e = counts[e], rowbase = offsets[e];

  __shared__ ushort As[2][128 * 32];
  __shared__ ushort Bs[2][128 * 32];

  const int tid = threadIdx.x;
  const int r0 = tid >> 2;
  const int ck = tid & 3;
  const int sch = (ck ^ ((r0 >> 1) & 3)) << 3;

  const int ar0 = mt * 128 + r0, ar1 = ar0 + 64;
  const int tok0 = rowTok[rowbase + (ar0 < n_e ? ar0 : n_e - 1)];
  const int tok1 = rowTok[rowbase + (ar1 < n_e ? ar1 : n_e - 1)];
  const ushort* pA0 = xb + (size_t)tok0 * HDIM + sch;
  const ushort* pA1 = xb + (size_t)tok1 * HDIM + sch;
  const size_t wbase = (size_t)e * IDIM * HDIM;
  const ushort* pB0 = wb + wbase + (size_t)(nt * 128 + r0) * HDIM + sch;
  const ushort* pB1 = wb + wbase + (size_t)(nt * 128 + r0 + 64) * HDIM + sch;

  const int lane = tid & 63;
  const int wid = tid >> 6;
  const int wr = (wid >> 1) << 6;
  const int wc = (wid & 1) << 6;
  const int lr = lane & 15;
  const int q = lane >> 4;

  f32x4 acc[4][4];
#pragma unroll
  for (int i = 0; i < 4; ++i)
#pragma unroll
    for (int j = 0; j < 4; ++j) acc[i][j] = (f32x4){0.f, 0.f, 0.f, 0.f};

  auto STAGE = [&](int b) {
    gload16(pA0, &As[b][tid * 8]);
    gload16(pA1, &As[b][2048 + tid * 8]);
    gload16(pB0, &Bs[b][tid * 8]);
    gload16(pB1, &Bs[b][2048 + tid * 8]);
    pA0 += 32; pA1 += 32; pB0 += 32; pB1 += 32;
  };

  const int NTK = HDIM / 32;  // 64
  STAGE(0);
  __syncthreads();
  int buf = 0;
  for (int kt = 0; kt < NTK; ++kt) {
    if (kt + 1 < NTK) STAGE(buf ^ 1);
    bf16x8 af[4], bfr[4];
#pragma unroll
    for (int mi = 0; mi < 4; ++mi)
      af[mi] = *(const bf16x8*)&As[buf][swzread(wr + mi * 16 + lr, q)];
#pragma unroll
    for (int ni = 0; ni < 4; ++ni)
      bfr[ni] = *(const bf16x8*)&Bs[buf][swzread(wc + ni * 16 + lr, q)];
#pragma unroll
    for (int mi = 0; mi < 4; ++mi)
#pragma unroll
      for (int ni = 0; ni < 4; ++ni)
        acc[mi][ni] = __builtin_amdgcn_mfma_f32_16x16x32_bf16(af[mi], bfr[ni], acc[mi][ni], 0, 0, 0);
    __syncthreads();
    buf ^= 1;
  }

#pragma unroll
  for (int mi = 0; mi < 4; ++mi) {
#pragma unroll
    for (int ni = 0; ni < 4; ++ni) {
      const int col = nt * 128 + wc + ni * 16 + lr;
#pragma unroll
      for (int r = 0; r < 4; ++r) {
        const int mrow = mt * 128 + wr + mi * 16 + q * 4 + r;
        if (mrow < n_e)
          outb[(size_t)(rowbase + mrow) * IDIM + col] = bf1(acc[mi][ni][r]);
      }
    }
  }
}

// ------- gemmB: po[rows][2048] = hbuf . w2^T  (pristine R15 body) -------
__global__ __launch_bounds__(256) void gemmB_kernel(
    const ushort* __restrict__ hb, const ushort* __restrict__ wb,
    const int* __restrict__ counts, const int* __restrict__ offsets,
    const int* __restrict__ nW, const int* __restrict__ wl,
    ushort* __restrict__ po)
{
  const int nTot = *nW;
  const int L = (blockIdx.x & 7) * (MAXBB / 8) + (blockIdx.x >> 3);
  if (L >= nTot) return;
  const int w = wl[L];
  const int e = w >> 12, nt = (w >> 6) & 63, mt = w & 63;
  const int n_e = counts[e], rowbase = offsets[e];

  __shared__ ushort As[2][128 * 32];
  __shared__ ushort Bs[2][128 * 32];

  const int tid = threadIdx.x;
  const int r0 = tid >> 2;
  const int ck = tid & 3;
  const int sch = (ck ^ ((r0 >> 1) & 3)) << 3;

  const int ar0 = mt * 128 + r0, ar1 = ar0 + 64;
  const int g0 = rowbase + (ar0 < n_e ? ar0 : n_e - 1);
  const int g1 = rowbase + (ar1 < n_e ? ar1 : n_e - 1);
  const ushort* pA0 = hb + (size_t)g0 * IDIM + sch;
  const ushort* pA1 = hb + (size_t)g1 * IDIM + sch;
  const size_t wbase = (size_t)e * HDIM * IDIM;
  const ushort* pB0 = wb + wbase + (size_t)(nt * 128 + r0) * IDIM + sch;
  const ushort* pB1 = wb + wbase + (size_t)(nt * 128 + r0 + 64) * IDIM + sch;

  const int lane = tid & 63;
  const int wid = tid >> 6;
  const int wr = (wid >> 1) << 6;
  const int wc = (wid & 1) << 6;
  const int lr = lane & 15;
  const int q = lane >> 4;

  f32x4 acc[4][4];
#pragma unroll
  for (int i = 0; i < 4; ++i)
#pragma unroll
    for (int j = 0; j < 4; ++j) acc[i][j] = (f32x4){0.f, 0.f, 0.f, 0.f};

  auto STAGE = [&](int b) {
    gload16(pA0, &As[b][tid * 8]);
    gload16(pA1, &As[b][2048 + tid * 8]);
    gload16(pB0, &Bs[b][tid * 8]);
    gload16(pB1, &Bs[b][2048 + tid * 8]);
    pA0 += 32; pA1 += 32; pB0 += 32; pB1 += 32;
  };

  const int NTK = IDIM / 32;  // 32
  STAGE(0);
  __syncthreads();
  int buf = 0;
  for (int kt = 0; kt < NTK; ++kt) {
    if (kt + 1 < NTK) STAGE(buf ^ 1);
    bf16x8 af[4], bfr[4];
#pragma unroll
    for (int mi = 0; mi < 4; ++mi)
      af[mi] = *(const bf16x8*)&As[buf][swzread(wr + mi * 16 + lr, q)];
#pragma unroll
    for (int ni = 0; ni < 4; ++ni)
      bfr[ni] = *(const bf16x8*)&Bs[buf][swzread(wc + ni * 16 + lr, q)];
#pragma unroll
    for (int mi = 0; mi < 4; ++mi)
#pragma unroll
      for (int ni = 0; ni < 4; ++ni)
        acc[mi][ni] = __builtin_amdgcn_mfma_f32_16x16x32_bf16(af[mi], bfr[ni], acc[mi][ni], 0, 0, 0);
    __syncthreads();
    buf ^= 1;
  }

#pragma unroll
  for (int mi = 0; mi < 4; ++mi) {
#pragma unroll
    for (int ni = 0; ni < 4; ++ni) {
      const int col = nt * 128 + wc + ni * 16 + lr;
#pragma unroll
      for (int r = 0; r < 4; ++r) {
        const int mrow = mt * 128 + wr + mi * 16 + q * 4 + r;
        if (mrow < n_e)
          po[(size_t)(rowbase + mrow) * HDIM + col] = bf1(acc[mi][ni][r]);
      }
    }
  }
}

// ---------------- silu: h = silu(g) * u, elementwise bf16 ----------------
__global__ __launch_bounds__(256) void silu_kernel(
    const ushort* __restrict__ g, const ushort* __restrict__ u,
    ushort* __restrict__ h, int n8)
{
  const int stride = gridDim.x * 256;
  for (int i = blockIdx.x * 256 + threadIdx.x; i < n8; i += stride) {
    u32x4 gv = __builtin_nontemporal_load(((const u32x4*)g) + i);
    u32x4 uv = __builtin_nontemporal_load(((const u32x4*)u) + i);
    uint4 hv;
#pragma unroll
    for (int wd = 0; wd < 4; ++wd) {
      const uint32_t gw2 = gv[wd], uw2 = uv[wd];
      const float g0 = bf2f((ushort)(gw2 & 0xffff));
      const float g1 = bf2f((ushort)(gw2 >> 16));
      const float u0 = bf2f((ushort)(uw2 & 0xffff));
      const float u1 = bf2f((ushort)(uw2 >> 16));
      const float h0 = (g0 / (1.f + __expf(-g0))) * u0;
      const float h1 = (g1 / (1.f + __expf(-g1))) * u1;
      (&hv.x)[wd] = pack2(h0, h1);
    }
    ((uint4*)h)[i] = hv;
  }
}

// ---------------- combine: out[t] = sum_k w_k * po[row_k] -----------------
__global__ __launch_bounds__(256) void combine_kernel(
    const ushort* __restrict__ po, const int* __restrict__ inv,
    const float* __restrict__ tw, float* __restrict__ out)
{
  const int t = blockIdx.x;
  const int r0 = inv[t * 4 + 0], r1 = inv[t * 4 + 1];
  const int r2 = inv[t * 4 + 2], r3 = inv[t * 4 + 3];
  const float w0 = tw[t * 4 + 0], w1 = tw[t * 4 + 1];
  const float w2v = tw[t * 4 + 2], w3 = tw[t * 4 + 3];
  const int i = threadIdx.x;
  uint4 v0 = *(const uint4*)(po + (size_t)r0 * HDIM + i * 8);
  uint4 v1 = *(const uint4*)(po + (size_t)r1 * HDIM + i * 8);
  uint4 v2 = *(const uint4*)(po + (size_t)r2 * HDIM + i * 8);
  uint4 v3 = *(const uint4*)(po + (size_t)r3 * HDIM + i * 8);
  float o[8];
#pragma unroll
  for (int w = 0; w < 4; ++w) {
    const uint32_t a = (&v0.x)[w], b = (&v1.x)[w], c = (&v2.x)[w], d = (&v3.x)[w];
    o[w * 2 + 0] = w0 * __builtin_bit_cast(float, a << 16) +
                   w1 * __builtin_bit_cast(float, b << 16) +
                   w2v * __builtin_bit_cast(float, c << 16) +
                   w3 * __builtin_bit_cast(float, d << 16);
    o[w * 2 + 1] = w0 * __builtin_bit_cast(float, a & 0xffff0000u) +
                   w1 * __builtin_bit_cast(float, b & 0xffff0000u) +
                   w2v * __builtin_bit_cast(float, c & 0xffff0000u) +
                   w3 * __builtin_bit_cast(float, d & 0xffff0000u);
  }
  float4* o4 = (float4*)(out + (size_t)t * HDIM + i * 8);
  o4[0] = (float4){o[0], o[1], o[2], o[3]};
  o4[1] = (float4){o[4], o[5], o[6], o[7]};
}

extern "C" void kernel_launch(void* const* d_in, const int* in_sizes, int n_in,
                              void* d_out, int out_size, void* d_ws, size_t ws_size,
                              hipStream_t stream) {
  const float* x   = (const float*)d_in[0];
  const float* gw  = (const float*)d_in[1];
  const float* w1g = (const float*)d_in[2];
  const float* w1u = (const float*)d_in[3];
  const float* w2  = (const float*)d_in[4];
  float* out = (float*)d_out;

  char* ws = (char*)d_ws;
  // layout (bytes): xb 8MB @0; wbufG 64MB @8M; wbufU 64MB @72M;
  // wbuf2 64MB @136M; gbuf 16MB @200M; ubuf 16MB @216M; hbuf 16MB @232M;
  // po 32MB @248M; idx @280M; ctrl @281M.  (~282MB < ws 512MB)
  ushort* xb    = (ushort*)(ws + 0);
  ushort* wbufG = (ushort*)(ws + 8388608);
  ushort* wbufU = (ushort*)(ws + 75497472);
  ushort* wbuf2 = (ushort*)(ws + 142606336);
  ushort* gbuf  = (ushort*)(ws + 209715200);
  ushort* ubuf  = (ushort*)(ws + 226492416);
  ushort* hbuf  = (ushort*)(ws + 243269632);
  ushort* po    = (ushort*)(ws + 260046848);
  int*    tkid   = (int*)(ws + 293601280);
  float*  tkw    = (float*)(ws + 293601280 + 32768);
  int*    rowTok = (int*)(ws + 293601280 + 65536);
  int*    inv    = (int*)(ws + 293601280 + 98304);
  int*    ctrl   = (int*)(ws + 293732352);
  int* counts  = ctrl;           // 16
  int* offsets = ctrl + 32;      // 17
  int* nWA     = ctrl + 50;      // 1
  int* nWB     = ctrl + 51;      // 1
  int* wlA     = ctrl + 64;      // MAXBA (640)
  int* wlB     = ctrl + 64 + MAXBA;  // MAXBB (1280)

  // router + cvt(w1g) overlap
  router_kernel<<<TTOK / 4 + NCVT, 256, 0, stream>>>(x, gw, xb, tkid, tkw,
                                                     w1g, wbufG);
  plan_scatter_kernel<<<1, 1024, 0, stream>>>(tkid, counts, offsets, nWA, nWB,
                                              wlA, wlB, rowTok, inv);
  // gate pass (reads wbufG) + cvt(w1u) overlap
  gemmA_kernel<<<MAXBA + NCVT, 256, 0, stream>>>(xb, wbufG, rowTok, counts,
                                                 offsets, nWA, wlA, gbuf,
                                                 w1u, wbufU);
  // up pass (reads wbufU) + cvt(w2) overlap
  gemmA_kernel<<<MAXBA + NCVT, 256, 0, stream>>>(xb, wbufU, rowTok, counts,
                                                 offsets, nWA, wlA, ubuf,
                                                 w2, wbuf2);
  // h = silu(g) * u
  silu_kernel<<<2048, 256, 0, stream>>>(gbuf, ubuf, hbuf, (TTOK * KSEL * IDIM) / 8);
  // down pass (reads wbuf2)
  gemmB_kernel<<<MAXBB, 256, 0, stream>>>(hbuf, wbuf2, counts, offsets,
                                          nWB, wlB, po);
  combine_kernel<<<TTOK, 256, 0, stream>>>(po, inv, tkw, out);
}

// Round 19
// 327.035 us; speedup vs baseline: 1.3467x; 1.0704x over previous
//
#include <hip/hip_runtime.h>
#include <hip/hip_bf16.h>
#include <stdint.h>

#define NEXP 16
#define KSEL 4
#define HDIM 2048
#define IDIM 1024
#define TTOK 2048
#define MAXTILES 80
#define NTA 8                    // gemmA n-tiles (IDIM/128)
#define NTB 16                   // gemmB n-tiles (HDIM/128)
#define MAXBA (MAXTILES * NTA)   // 640
#define MAXBB (MAXTILES * NTB)   // 1280
#define NCVT 1024                // piggyback cvt blocks per stream
#define NW8 ((NEXP * IDIM * HDIM) / 8)

typedef __attribute__((ext_vector_type(8))) short bf16x8;
typedef __attribute__((ext_vector_type(4))) float f32x4;
typedef __attribute__((ext_vector_type(4))) unsigned int u32x4;
typedef unsigned int u32;

__device__ __forceinline__ uint32_t pack2(float a, float b) {
  __hip_bfloat162 h = __float22bfloat162_rn(float2{a, b});
  uint32_t u;
  __builtin_memcpy(&u, &h, 4);
  return u;
}
__device__ __forceinline__ ushort bf1(float a) {
  __hip_bfloat16 h = __float2bfloat16(a);
  ushort u;
  __builtin_memcpy(&u, &h, 2);
  return u;
}
__device__ __forceinline__ float bf2f(ushort u) {
  uint32_t v = (uint32_t)u << 16;
  float f;
  __builtin_memcpy(&f, &v, 4);
  return f;
}
// async global->LDS, 16B per lane; linear dest, per-lane (gathered/swizzled)
// source address (m97/m173 pattern).
__device__ __forceinline__ void gload16(const void* g, void* l) {
  __builtin_amdgcn_global_load_lds(
      (const __attribute__((address_space(1))) u32*)g,
      (__attribute__((address_space(3))) u32*)l, 16, 0, 0);
}
// bf16 tile [rows][32 bf16]: stored linear, source chunk pre-XOR'd,
// read chunk XOR'd -> conflict-free (0 conflicts verified R3-R18).
__device__ __forceinline__ int swzread(int row, int q) {
  return row * 32 + ((q ^ ((row >> 1) & 3)) << 3);
}
// fp32 -> bf16 streaming body (NT loads), grid-strided over nblk blocks.
__device__ __forceinline__ void cvt_body(const float* __restrict__ src,
                                         ushort* __restrict__ dst,
                                         int blk, int nblk) {
  const int stride = nblk * 256;
  for (int i = blk * 256 + (int)threadIdx.x; i < NW8; i += stride) {
    f32x4 a = __builtin_nontemporal_load(((const f32x4*)src) + i * 2);
    f32x4 b = __builtin_nontemporal_load(((const f32x4*)src) + i * 2 + 1);
    uint4 t;
    t.x = pack2(a[0], a[1]); t.y = pack2(a[2], a[3]);
    t.z = pack2(b[0], b[1]); t.w = pack2(b[2], b[3]);
    ((uint4*)dst)[i] = t;
  }
}

// -- router (blocks 0..511) + piggyback cvt w1g AND cvt w1u (blocks 512+) --
__global__ __launch_bounds__(256) void router_kernel(
    const float* __restrict__ x, const float* __restrict__ gw,
    ushort* __restrict__ xb, int* __restrict__ topk_id,
    float* __restrict__ topk_w,
    const float* __restrict__ srcG, ushort* __restrict__ dstG,
    const float* __restrict__ srcU, ushort* __restrict__ dstU)
{
  if (blockIdx.x >= TTOK / 4 + NCVT) {
    cvt_body(srcU, dstU, blockIdx.x - (TTOK / 4 + NCVT), NCVT);
    return;
  }
  if (blockIdx.x >= TTOK / 4) {
    cvt_body(srcG, dstG, blockIdx.x - TTOK / 4, NCVT);
    return;
  }
  const int wid = threadIdx.x >> 6;
  const int lane = threadIdx.x & 63;
  const int t = blockIdx.x * 4 + wid;
  const float4* x4 = (const float4*)(x + (size_t)t * HDIM);
  const float4* gw4 = (const float4*)gw;
  float acc[NEXP];
#pragma unroll
  for (int e = 0; e < NEXP; ++e) acc[e] = 0.f;
#pragma unroll
  for (int i = 0; i < HDIM / 256; ++i) {
    const int idx = i * 64 + lane;
    float4 xv = x4[idx];
    uint2 xp;
    xp.x = pack2(xv.x, xv.y);
    xp.y = pack2(xv.z, xv.w);
    *(uint2*)(xb + (size_t)t * HDIM + idx * 4) = xp;
#pragma unroll
    for (int e = 0; e < NEXP; ++e) {
      float4 wv = gw4[e * (HDIM / 4) + idx];
      acc[e] += xv.x * wv.x + xv.y * wv.y + xv.z * wv.z + xv.w * wv.w;
    }
  }
#pragma unroll
  for (int e = 0; e < NEXP; ++e) {
#pragma unroll
    for (int off = 32; off >= 1; off >>= 1)
      acc[e] += __shfl_xor(acc[e], off);
  }
  if (lane == 0) {
    unsigned taken = 0;
    float vals[KSEL];
    int ids[KSEL];
#pragma unroll
    for (int k = 0; k < KSEL; ++k) {
      float bv = -3.4e38f; int bi = 0;
      for (int e = 0; e < NEXP; ++e)
        if (!((taken >> e) & 1u) && acc[e] > bv) { bv = acc[e]; bi = e; }
      taken |= 1u << bi; vals[k] = bv; ids[k] = bi;
    }
    float m = vals[0], s = 0.f, w[KSEL];
#pragma unroll
    for (int k = 0; k < KSEL; ++k) { w[k] = __expf(vals[k] - m); s += w[k]; }
    float is = 1.f / s;
#pragma unroll
    for (int k = 0; k < KSEL; ++k) {
      topk_id[t * KSEL + k] = ids[k];
      topk_w[t * KSEL + k] = w[k] * is;
    }
  }
}

// --- plan+scatter, single block: LDS histogram/cursors, no global atomics --
__global__ __launch_bounds__(1024) void plan_scatter_kernel(
    const int* __restrict__ topk_id, int* __restrict__ counts,
    int* __restrict__ offsets, int* __restrict__ nWA, int* __restrict__ nWB,
    int* __restrict__ wlA, int* __restrict__ wlB,
    int* __restrict__ rowTok, int* __restrict__ inv)
{
  __shared__ int cnt[NEXP], off[NEXP], cur[NEXP], tiles[NEXP], pre[NEXP];
  const int tid = threadIdx.x;
  if (tid < NEXP) { cnt[tid] = 0; cur[tid] = 0; }
  __syncthreads();
  for (int i = tid; i < TTOK * KSEL; i += 1024)
    atomicAdd(&cnt[topk_id[i]], 1);               // LDS atomics (fast)
  __syncthreads();
  if (tid == 0) {
    int s = 0, p = 0;
    for (int e = 0; e < NEXP; ++e) {
      off[e] = s; s += cnt[e];
      tiles[e] = (cnt[e] + 127) >> 7;
      pre[e] = p; p += tiles[e];
    }
    *nWA = p * NTA;
    *nWB = p * NTB;
  }
  __syncthreads();
  if (tid < NEXP) {
    counts[tid] = cnt[tid];
    offsets[tid] = off[tid];
    const int e = tid, T = tiles[e];
    int idx = pre[e] * NTA;
    for (int nt = 0; nt < NTA; ++nt)
      for (int mt = 0; mt < T; ++mt)
        wlA[idx++] = (e << 12) | (nt << 6) | mt;
  } else if (tid < 2 * NEXP) {
    const int e = tid - NEXP, T = tiles[e];
    int idx = pre[e] * NTB;
    for (int nt = 0; nt < NTB; ++nt)
      for (int mt = 0; mt < T; ++mt)
        wlB[idx++] = (e << 12) | (nt << 6) | mt;
  }
  for (int i = tid; i < TTOK * KSEL; i += 1024) {
    const int e = topk_id[i];
    const int pos = atomicAdd(&cur[e], 1);        // LDS atomic
    const int row = off[e] + pos;
    rowTok[row] = i >> 2;
    inv[i] = row;
  }
}

// -- gemmA merged: blocks [0,MAXBA)=gate(wG->gbuf), [MAXBA,2*MAXBA)=up
//    (wU->ubuf), [2*MAXBA,+NCVT)=cvt(w2). Uniform entry select; pristine
//    R15 GEMM body (2-buffer, __syncthreads), single instantiation. --------
__global__ __launch_bounds__(256) void gemmA_kernel(
    const ushort* __restrict__ xb,
    const ushort* __restrict__ wG, ushort* __restrict__ gbuf,
    const ushort* __restrict__ wU, ushort* __restrict__ ubuf,
    const int* __restrict__ rowTok, const int* __restrict__ counts,
    const int* __restrict__ offsets, const int* __restrict__ nW,
    const int* __restrict__ wl,
    const float* __restrict__ cvsrc, ushort* __restrict__ cvdst)
{
  int bid = blockIdx.x;
  if (bid >= 2 * MAXBA) {
    cvt_body(cvsrc, cvdst, bid - 2 * MAXBA, NCVT);
    return;
  }
  const ushort* wb;
  ushort* outb;
  if (bid >= MAXBA) { wb = wU; outb = ubuf; bid -= MAXBA; }
  else              { wb = wG; outb = gbuf; }

  const int nTot = *nW;
  const int L = (bid & 7) * (MAXBA / 8) + (bid >> 3);
  if (L >= nTot) return;
  const int w = wl[L];
  const int e = w >> 12, nt = (w >> 6) & 63, mt = w & 63;
  const int n_e = counts[e], rowbase = offsets[e];

  __shared__ ushort As[2][128 * 32];
  __shared__ ushort Bs[2][128 * 32];

  const int tid = threadIdx.x;
  const int r0 = tid >> 2;
  const int ck = tid & 3;
  const int sch = (ck ^ ((r0 >> 1) & 3)) << 3;

  const int ar0 = mt * 128 + r0, ar1 = ar0 + 64;
  const int tok0 = rowTok[rowbase + (ar0 < n_e ? ar0 : n_e - 1)];
  const int tok1 = rowTok[rowbase + (ar1 < n_e ? ar1 : n_e - 1)];
  const ushort* pA0 = xb + (size_t)tok0 * HDIM + sch;
  const ushort* pA1 = xb + (size_t)tok1 * HDIM + sch;
  const size_t wbase = (size_t)e * IDIM * HDIM;
  const ushort* pB0 = wb + wbase + (size_t)(nt * 128 + r0) * HDIM + sch;
  const ushort* pB1 = wb + wbase + (size_t)(nt * 128 + r0 + 64) * HDIM + sch;

  const int lane = tid & 63;
  const int wid = tid >> 6;
  const int wr = (wid >> 1) << 6;
  const int wc = (wid & 1) << 6;
  const int lr = lane & 15;
  const int q = lane >> 4;

  f32x4 acc[4][4];
#pragma unroll
  for (int i = 0; i < 4; ++i)
#pragma unroll
    for (int j = 0; j < 4; ++j) acc[i][j] = (f32x4){0.f, 0.f, 0.f, 0.f};

  auto STAGE = [&](int b) {
    gload16(pA0, &As[b][tid * 8]);
    gload16(pA1, &As[b][2048 + tid * 8]);
    gload16(pB0, &Bs[b][tid * 8]);
    gload16(pB1, &Bs[b][2048 + tid * 8]);
    pA0 += 32; pA1 += 32; pB0 += 32; pB1 += 32;
  };

  const int NTK = HDIM / 32;  // 64
  STAGE(0);
  __syncthreads();
  int buf = 0;
  for (int kt = 0; kt < NTK; ++kt) {
    if (kt + 1 < NTK) STAGE(buf ^ 1);
    bf16x8 af[4], bfr[4];
#pragma unroll
    for (int mi = 0; mi < 4; ++mi)
      af[mi] = *(const bf16x8*)&As[buf][swzread(wr + mi * 16 + lr, q)];
#pragma unroll
    for (int ni = 0; ni < 4; ++ni)
      bfr[ni] = *(const bf16x8*)&Bs[buf][swzread(wc + ni * 16 + lr, q)];
#pragma unroll
    for (int mi = 0; mi < 4; ++mi)
#pragma unroll
      for (int ni = 0; ni < 4; ++ni)
        acc[mi][ni] = __builtin_amdgcn_mfma_f32_16x16x32_bf16(af[mi], bfr[ni], acc[mi][ni], 0, 0, 0);
    __syncthreads();
    buf ^= 1;
  }

#pragma unroll
  for (int mi = 0; mi < 4; ++mi) {
#pragma unroll
    for (int ni = 0; ni < 4; ++ni) {
      const int col = nt * 128 + wc + ni * 16 + lr;
#pragma unroll
      for (int r = 0; r < 4; ++r) {
        const int mrow = mt * 128 + wr + mi * 16 + q * 4 + r;
        if (mrow < n_e)
          outb[(size_t)(rowbase + mrow) * IDIM + col] = bf1(acc[mi][ni][r]);
      }
    }
  }
}

// ------- gemmB: po[rows][2048] = hbuf . w2^T  (pristine R15 body) -------
__global__ __launch_bounds__(256) void gemmB_kernel(
    const ushort* __restrict__ hb, const ushort* __restrict__ wb,
    const int* __restrict__ counts, const int* __restrict__ offsets,
    const int* __restrict__ nW, const int* __restrict__ wl,
    ushort* __restrict__ po)
{
  const int nTot = *nW;
  const int L = (blockIdx.x & 7) * (MAXBB / 8) + (blockIdx.x >> 3);
  if (L >= nTot) return;
  const int w = wl[L];
  const int e = w >> 12, nt = (w >> 6) & 63, mt = w & 63;
  const int n_e = counts[e], rowbase = offsets[e];

  __shared__ ushort As[2][128 * 32];
  __shared__ ushort Bs[2][128 * 32];

  const int tid = threadIdx.x;
  const int r0 = tid >> 2;
  const int ck = tid & 3;
  const int sch = (ck ^ ((r0 >> 1) & 3)) << 3;

  const int ar0 = mt * 128 + r0, ar1 = ar0 + 64;
  const int g0 = rowbase + (ar0 < n_e ? ar0 : n_e - 1);
  const int g1 = rowbase + (ar1 < n_e ? ar1 : n_e - 1);
  const ushort* pA0 = hb + (size_t)g0 * IDIM + sch;
  const ushort* pA1 = hb + (size_t)g1 * IDIM + sch;
  const size_t wbase = (size_t)e * HDIM * IDIM;
  const ushort* pB0 = wb + wbase + (size_t)(nt * 128 + r0) * IDIM + sch;
  const ushort* pB1 = wb + wbase + (size_t)(nt * 128 + r0 + 64) * IDIM + sch;

  const int lane = tid & 63;
  const int wid = tid >> 6;
  const int wr = (wid >> 1) << 6;
  const int wc = (wid & 1) << 6;
  const int lr = lane & 15;
  const int q = lane >> 4;

  f32x4 acc[4][4];
#pragma unroll
  for (int i = 0; i < 4; ++i)
#pragma unroll
    for (int j = 0; j < 4; ++j) acc[i][j] = (f32x4){0.f, 0.f, 0.f, 0.f};

  auto STAGE = [&](int b) {
    gload16(pA0, &As[b][tid * 8]);
    gload16(pA1, &As[b][2048 + tid * 8]);
    gload16(pB0, &Bs[b][tid * 8]);
    gload16(pB1, &Bs[b][2048 + tid * 8]);
    pA0 += 32; pA1 += 32; pB0 += 32; pB1 += 32;
  };

  const int NTK = IDIM / 32;  // 32
  STAGE(0);
  __syncthreads();
  int buf = 0;
  for (int kt = 0; kt < NTK; ++kt) {
    if (kt + 1 < NTK) STAGE(buf ^ 1);
    bf16x8 af[4], bfr[4];
#pragma unroll
    for (int mi = 0; mi < 4; ++mi)
      af[mi] = *(const bf16x8*)&As[buf][swzread(wr + mi * 16 + lr, q)];
#pragma unroll
    for (int ni = 0; ni < 4; ++ni)
      bfr[ni] = *(const bf16x8*)&Bs[buf][swzread(wc + ni * 16 + lr, q)];
#pragma unroll
    for (int mi = 0; mi < 4; ++mi)
#pragma unroll
      for (int ni = 0; ni < 4; ++ni)
        acc[mi][ni] = __builtin_amdgcn_mfma_f32_16x16x32_bf16(af[mi], bfr[ni], acc[mi][ni], 0, 0, 0);
    __syncthreads();
    buf ^= 1;
  }

#pragma unroll
  for (int mi = 0; mi < 4; ++mi) {
#pragma unroll
    for (int ni = 0; ni < 4; ++ni) {
      const int col = nt * 128 + wc + ni * 16 + lr;
#pragma unroll
      for (int r = 0; r < 4; ++r) {
        const int mrow = mt * 128 + wr + mi * 16 + q * 4 + r;
        if (mrow < n_e)
          po[(size_t)(rowbase + mrow) * HDIM + col] = bf1(acc[mi][ni][r]);
      }
    }
  }
}

// ---------------- silu: h = silu(g) * u, elementwise bf16 ----------------
__global__ __launch_bounds__(256) void silu_kernel(
    const ushort* __restrict__ g, const ushort* __restrict__ u,
    ushort* __restrict__ h, int n8)
{
  const int stride = gridDim.x * 256;
  for (int i = blockIdx.x * 256 + threadIdx.x; i < n8; i += stride) {
    u32x4 gv = __builtin_nontemporal_load(((const u32x4*)g) + i);
    u32x4 uv = __builtin_nontemporal_load(((const u32x4*)u) + i);
    uint4 hv;
#pragma unroll
    for (int wd = 0; wd < 4; ++wd) {
      const uint32_t gw2 = gv[wd], uw2 = uv[wd];
      const float g0 = bf2f((ushort)(gw2 & 0xffff));
      const float g1 = bf2f((ushort)(gw2 >> 16));
      const float u0 = bf2f((ushort)(uw2 & 0xffff));
      const float u1 = bf2f((ushort)(uw2 >> 16));
      const float h0 = (g0 / (1.f + __expf(-g0))) * u0;
      const float h1 = (g1 / (1.f + __expf(-g1))) * u1;
      (&hv.x)[wd] = pack2(h0, h1);
    }
    ((uint4*)h)[i] = hv;
  }
}

// ---------------- combine: out[t] = sum_k w_k * po[row_k] -----------------
__global__ __launch_bounds__(256) void combine_kernel(
    const ushort* __restrict__ po, const int* __restrict__ inv,
    const float* __restrict__ tw, float* __restrict__ out)
{
  const int t = blockIdx.x;
  const int r0 = inv[t * 4 + 0], r1 = inv[t * 4 + 1];
  const int r2 = inv[t * 4 + 2], r3 = inv[t * 4 + 3];
  const float w0 = tw[t * 4 + 0], w1 = tw[t * 4 + 1];
  const float w2v = tw[t * 4 + 2], w3 = tw[t * 4 + 3];
  const int i = threadIdx.x;
  uint4 v0 = *(const uint4*)(po + (size_t)r0 * HDIM + i * 8);
  uint4 v1 = *(const uint4*)(po + (size_t)r1 * HDIM + i * 8);
  uint4 v2 = *(const uint4*)(po + (size_t)r2 * HDIM + i * 8);
  uint4 v3 = *(const uint4*)(po + (size_t)r3 * HDIM + i * 8);
  float o[8];
#pragma unroll
  for (int w = 0; w < 4; ++w) {
    const uint32_t a = (&v0.x)[w], b = (&v1.x)[w], c = (&v2.x)[w], d = (&v3.x)[w];
    o[w * 2 + 0] = w0 * __builtin_bit_cast(float, a << 16) +
                   w1 * __builtin_bit_cast(float, b << 16) +
                   w2v * __builtin_bit_cast(float, c << 16) +
                   w3 * __builtin_bit_cast(float, d << 16);
    o[w * 2 + 1] = w0 * __builtin_bit_cast(float, a & 0xffff0000u) +
                   w1 * __builtin_bit_cast(float, b & 0xffff0000u) +
                   w2v * __builtin_bit_cast(float, c & 0xffff0000u) +
                   w3 * __builtin_bit_cast(float, d & 0xffff0000u);
  }
  float4* o4 = (float4*)(out + (size_t)t * HDIM + i * 8);
  o4[0] = (float4){o[0], o[1], o[2], o[3]};
  o4[1] = (float4){o[4], o[5], o[6], o[7]};
}

extern "C" void kernel_launch(void* const* d_in, const int* in_sizes, int n_in,
                              void* d_out, int out_size, void* d_ws, size_t ws_size,
                              hipStream_t stream) {
  const float* x   = (const float*)d_in[0];
  const float* gw  = (const float*)d_in[1];
  const float* w1g = (const float*)d_in[2];
  const float* w1u = (const float*)d_in[3];
  const float* w2  = (const float*)d_in[4];
  float* out = (float*)d_out;

  char* ws = (char*)d_ws;
  // layout (bytes): xb 8MB @0; wbufG 64MB @8M; wbufU 64MB @72M;
  // wbuf2 64MB @136M; gbuf 16MB @200M; ubuf 16MB @216M; hbuf 16MB @232M;
  // po 32MB @248M; idx @280M; ctrl @281M.
  ushort* xb    = (ushort*)(ws + 0);
  ushort* wbufG = (ushort*)(ws + 8388608);
  ushort* wbufU = (ushort*)(ws + 75497472);
  ushort* wbuf2 = (ushort*)(ws + 142606336);
  ushort* gbuf  = (ushort*)(ws + 209715200);
  ushort* ubuf  = (ushort*)(ws + 226492416);
  ushort* hbuf  = (ushort*)(ws + 243269632);
  ushort* po    = (ushort*)(ws + 260046848);
  int*    tkid   = (int*)(ws + 293601280);
  float*  tkw    = (float*)(ws + 293601280 + 32768);
  int*    rowTok = (int*)(ws + 293601280 + 65536);
  int*    inv    = (int*)(ws + 293601280 + 98304);
  int*    ctrl   = (int*)(ws + 293732352);
  int* counts  = ctrl;           // 16
  int* offsets = ctrl + 32;      // 17
  int* nWA     = ctrl + 50;      // 1
  int* nWB     = ctrl + 51;      // 1
  int* wlA     = ctrl + 64;      // MAXBA (640)
  int* wlB     = ctrl + 64 + MAXBA;  // MAXBB (1280)

  // router + cvt(w1g) + cvt(w1u) overlap
  router_kernel<<<TTOK / 4 + 2 * NCVT, 256, 0, stream>>>(
      x, gw, xb, tkid, tkw, w1g, wbufG, w1u, wbufU);
  plan_scatter_kernel<<<1, 1024, 0, stream>>>(tkid, counts, offsets, nWA, nWB,
                                              wlA, wlB, rowTok, inv);
  // merged gate+up GEMM + cvt(w2) overlap
  gemmA_kernel<<<2 * MAXBA + NCVT, 256, 0, stream>>>(
      xb, wbufG, gbuf, wbufU, ubuf, rowTok, counts, offsets, nWA, wlA,
      w2, wbuf2);
  // h = silu(g) * u
  silu_kernel<<<2048, 256, 0, stream>>>(gbuf, ubuf, hbuf, (TTOK * KSEL * IDIM) / 8);
  // down pass (reads wbuf2)
  gemmB_kernel<<<MAXBB, 256, 0, stream>>>(hbuf, wbuf2, counts, offsets,
                                          nWB, wlB, po);
  combine_kernel<<<TTOK, 256, 0, stream>>>(po, inv, tkw, out);
}